// Round 7
// baseline (463.570 us; speedup 1.0000x reference)
//
#include <hip/hip_runtime.h>
#include <math.h>

#define B_ 16
#define W_ 512
#define H_ 512
#define S_ (W_*H_)
#define ALPHA_ 0.15f
#define MU_ 10.0f
#define TAU_ 0.125f
#define SIG_ 0.125f
#define EPS_ 1e-6f
#define INV1PT_ (1.0f/(1.0f+TAU_))
#define NBINS 4096
#define BINSCALE 2048.0f
#define BINW (1.0f/2048.0f)

// ---- K1: horizontal 31-tap max via log-tree sliding max (float4 staging) ----
__global__ __launch_bounds__(256) void hmax_kernel(const float* __restrict__ Iy,
                                                   float* __restrict__ Rh,
                                                   float* __restrict__ GBh){
  __shared__ float bufA[2][544], bufB[2][544];
  int t = threadIdx.x;
  int b = blockIdx.x >> 9;
  int i = blockIdx.x & 511;
  const float* rowR = Iy + (size_t)b*3*S_ + (size_t)i*W_;
  const float* rowG = rowR + S_;
  const float* rowB = rowR + 2*S_;
  // interior: p4 in [4,132) -> buf[p4*4 .. +3] = row[p4*4-16 ..], 16B-aligned
  if (t < 128){
    int o4 = (t + 4)*4;
    float4 r = *(const float4*)&rowR[o4-16];
    float4 g = *(const float4*)&rowG[o4-16];
    float4 bb = *(const float4*)&rowB[o4-16];
    *(float4*)&bufA[0][o4] = r;
    *(float4*)&bufA[1][o4] = make_float4(fmaxf(g.x,bb.x), fmaxf(g.y,bb.y),
                                         fmaxf(g.z,bb.z), fmaxf(g.w,bb.w));
  } else if (t < 160){
    int e = t - 128;                       // 32 edge slots: [0,16) u [528,544)
    int p = (e < 16) ? e : (512 + e);
    bufA[0][p] = -1e30f;
    bufA[1][p] = -1e30f;
  }
  __syncthreads();
  float (*src)[544] = bufA; float (*dst)[544] = bufB;
  const int ds[5] = {1, 2, 4, 8, 15};
  #pragma unroll
  for (int sstep = 0; sstep < 5; ++sstep){
    int d = ds[sstep];
    for (int p = t; p < 544; p += 256){
      int q = min(p + d, 543);
      dst[0][p] = fmaxf(src[0][p], src[0][q]);
      dst[1][p] = fmaxf(src[1][p], src[1][q]);
    }
    __syncthreads();
    float (*tmp)[544] = src; src = dst; dst = tmp;
  }
  size_t o = (size_t)b*S_ + (size_t)i*W_;
  for (int p = t; p < 512; p += 256){
    Rh[o+p]  = src[0][p+1];
    GBh[o+p] = src[1][p+1];
  }
}

// ---- vertical van Herk forward scan (31-row aligned chunks; static trip) ----
__global__ __launch_bounds__(256) void vscan_fwd_kernel(const float* __restrict__ Rh,
                                                        const float* __restrict__ GBh,
                                                        float* __restrict__ Rf,
                                                        float* __restrict__ Gf){
  int gid = blockIdx.x*256 + threadIdx.x;     // 544 blocks = 8192 cols * 17 chunks
  int col = gid & 8191;
  int c   = gid >> 13;                        // 0..16
  int b = col >> 9, j = col & 511;
  int i0 = c*31;
  size_t base = (size_t)b*S_ + j;
  float rR = -1e30f, rG = -1e30f;
  if (c <= 15){
    for (int k = 0; k < 31; ++k){
      size_t o = base + (size_t)(i0+k)*W_;
      rR = fmaxf(rR, Rh[o]); rG = fmaxf(rG, GBh[o]);
      Rf[o] = rR; Gf[o] = rG;
    }
  } else {
    for (int k = 0; k < 16; ++k){
      size_t o = base + (size_t)(i0+k)*W_;
      rR = fmaxf(rR, Rh[o]); rG = fmaxf(rG, GBh[o]);
      Rf[o] = rR; Gf[o] = rG;
    }
  }
}

// ---- vertical bwd scan; x = |Rmax - GBmax| + R; FUSED x-histogram ----
__global__ __launch_bounds__(256) void vscan_bwd_kernel(const float* __restrict__ Rh,
                                                        const float* __restrict__ GBh,
                                                        const float* __restrict__ Rf,
                                                        const float* __restrict__ Gf,
                                                        const float* __restrict__ Iy,
                                                        float* __restrict__ xo,
                                                        unsigned int* __restrict__ hist){
  __shared__ unsigned int h[NBINS];
  int t = threadIdx.x;
  for (int p = t; p < NBINS; p += 256) h[p] = 0u;
  __syncthreads();
  int gid = blockIdx.x*256 + t;
  int col = gid & 8191;
  int c   = gid >> 13;
  int b = col >> 9, j = col & 511;
  int half = j >> 8;                           // uniform per block
  int i0 = c*31;
  size_t base = (size_t)b*S_ + j;
  const float* IyR = Iy + (size_t)b*3*S_ + j;
  float lR = -1e30f, lG = -1e30f;

  #define BWD_BODY(I, BI)                                          \
    { int i_ = (I);                                                \
      size_t o64 = base + (size_t)i_*W_;                           \
      lR = fmaxf(lR, Rh[o64]); lG = fmaxf(lG, GBh[o64]);           \
      int o_ = i_ + 15;                                            \
      size_t ob = base + (size_t)(BI)*W_;                          \
      float mR = fmaxf(lR, Rf[ob]);                                \
      float mG = fmaxf(lG, Gf[ob]);                                \
      float xv = fabsf(mR - mG) + IyR[(size_t)o_*W_];              \
      xo[base + (size_t)o_*W_] = xv;                               \
      int bin = (int)(xv*BINSCALE);                                \
      bin = min(max(bin, 0), NBINS-1);                             \
      atomicAdd(&h[bin], 1u); }

  if (c <= 14){
    // full chunk: o = i+15 <= 479 < 512 always; bi = i+30 <= 494 < 511 always
    for (int k = 30; k >= 0; --k) BWD_BODY(i0+k, i0+k+30)
  } else if (c == 15){
    // full chunk: o <= 510 < 512 always; bi needs the 511 clamp
    for (int k = 30; k >= 0; --k) BWD_BODY(i0+k, min(i0+k+30, H_-1))
  } else {
    // c == 16: 16 rows, only i=496 emits (o=511)
    for (int i = H_-1; i >= i0; --i){
      size_t o64 = base + (size_t)i*W_;
      lR = fmaxf(lR, Rh[o64]); lG = fmaxf(lG, GBh[o64]);
      int o = i + 15;
      if (o < H_){
        size_t ob = base + (size_t)(H_-1)*W_;
        float mR = fmaxf(lR, Rf[ob]);
        float mG = fmaxf(lG, Gf[ob]);
        float xv = fabsf(mR - mG) + IyR[(size_t)o*W_];
        xo[base + (size_t)o*W_] = xv;
        int bin = (int)(xv*BINSCALE);
        bin = min(max(bin, 0), NBINS-1);
        atomicAdd(&h[bin], 1u);
      }
    }
  }
  if (c == 0){
    for (int o = 0; o < 15; ++o){
      size_t ob = base + (size_t)(o+15)*W_;
      float mR = Rf[ob], mG = Gf[ob];
      float xv = fabsf(mR - mG) + IyR[(size_t)o*W_];
      xo[base + (size_t)o*W_] = xv;
      int bin = (int)(xv*BINSCALE);
      bin = min(max(bin, 0), NBINS-1);
      atomicAdd(&h[bin], 1u);
    }
  }
  __syncthreads();
  unsigned int* hb = hist + (size_t)(b*34 + c*2 + half)*NBINS;
  for (int q = t; q < NBINS; q += 256) hb[q] = h[q];
}

// ---- FUSED: N_hat store + grad-mag histogram in one pass over xb ----
__global__ __launch_bounds__(256) void nhat_gmhist_kernel(const float* __restrict__ xb,
                                                          const float* __restrict__ vx2,
                                                          float* __restrict__ nh,
                                                          unsigned int* __restrict__ hist){
  __shared__ unsigned int h[NBINS];
  int t = threadIdx.x;
  int b = blockIdx.x >> 4, sub = blockIdx.x & 15;
  for (int p = t; p < NBINS; p += 256) h[p] = 0u;
  __syncthreads();
  float lo = vx2[2*b], hi = vx2[2*b+1];
  float inv = 1.0f/(hi - lo + EPS_);
  const float* base = xb + (size_t)b*S_;
  float* nhb = nh + (size_t)b*S_;
  int i0 = sub*16384;
  for (int k = 0; k < 64; ++k){
    int idx = i0 + k*256 + t;
    int row = idx >> 9, col = idx & 511;
    float c = fminf(fmaxf((base[idx] - lo)*inv, 0.f), 1.f);
    float dx = 0.f, dy = 0.f;
    if (col < W_-1) dx = fminf(fmaxf((base[idx+1]  - lo)*inv, 0.f), 1.f) - c;
    if (row < H_-1) dy = fminf(fmaxf((base[idx+W_] - lo)*inv, 0.f), 1.f) - c;
    nhb[idx] = c;
    float g = sqrtf(dx*dx + dy*dy + EPS_);
    int bin = (int)(g*BINSCALE);
    bin = min(max(bin, 0), NBINS-1);
    atomicAdd(&h[bin], 1u);
  }
  __syncthreads();
  unsigned int* hb = hist + (size_t)(b*16 + sub)*NBINS;
  for (int q = t; q < NBINS; q += 256) hb[q] = h[q];
}

// ---- pick order statistics (nsub partials per batch) ----
__global__ __launch_bounds__(256) void pick_hist_kernel(
    const unsigned int* __restrict__ hist, int nsub,
    int r0, int r1, int r2, int r3,
    int nranks, float* __restrict__ outv, int which){
  __shared__ unsigned int part[256];
  __shared__ int s_own[4], s_rem[4];
  __shared__ float s_val[4];
  int t = threadIdx.x, b = blockIdx.x;
  const unsigned int* hb = hist + (size_t)b*nsub*NBINS;
  unsigned int binc[16];
  #pragma unroll
  for (int k = 0; k < 16; ++k) binc[k] = 0u;
  for (int sub = 0; sub < nsub; ++sub){
    const unsigned int* hp = hb + (size_t)sub*NBINS + t*16;
    #pragma unroll
    for (int k = 0; k < 16; ++k) binc[k] += hp[k];
  }
  unsigned int sum = 0u;
  #pragma unroll
  for (int k = 0; k < 16; ++k) sum += binc[k];
  part[t] = sum;
  __syncthreads();
  if (t == 0){
    int rk[4] = {r0, r1, r2, r3};
    for (int ri = 0; ri < nranks; ++ri){
      int rem = rk[ri]; int own = 255;
      for (int q = 0; q < 256; ++q){
        if ((unsigned int)rem < part[q]){ own = q; break; }
        rem -= (int)part[q];
      }
      s_own[ri] = own; s_rem[ri] = rem;
    }
  }
  __syncthreads();
  for (int ri = 0; ri < nranks; ++ri){
    if (t == s_own[ri]){
      int rem = s_rem[ri]; int bin = t*16 + 15;
      #pragma unroll
      for (int q = 0; q < 16; ++q){
        if ((unsigned int)rem < binc[q]){ bin = t*16 + q; break; }
        rem -= (int)binc[q];
      }
      s_val[ri] = ((float)bin + 0.5f) * BINW;
    }
  }
  __syncthreads();
  if (t == 0){
    if (which == 0){
      outv[2*b+0] = s_val[0]*0.57f + s_val[1]*0.43f;   // lo (pos frac .43)
      outv[2*b+1] = s_val[2]*0.43f + s_val[3]*0.57f;   // hi (pos frac .57)
    } else {
      outv[b] = fmaxf(0.5f*(s_val[0] + s_val[1]), EPS_); // median -> sigma
    }
  }
}

// ---- fused primal-dual: 3 launches of T=10; 64x64 tile, asym halo ----
// HY=10 (CY 44), HX=12 (CX 40, mult of 4). Hot loop arithmetic identical to the
// verified round-5 body; T-loop unrolled by 2 so buffer roles are compile-time
// (no per-iter pointer selects) and the dead last publish+barrier is peeled.
#define TY 64
#define TX 64
#define HY 10
#define HX 12
#define CY 44
#define CX 40
#define NBY 12   // ceil(512/44)
#define NBX 13   // ceil(512/40)
#define PSTR 68  // padded LDS row stride (float4-aligned)

#define AW_(d) (ALPHA_*(1.0f + MU_*__expf(-fabsf(d)*invs)))

__global__ __launch_bounds__(1024, 2) void pd_fused_kernel(
    const float* __restrict__ u_in,  const float* __restrict__ ub_in,
    const float* __restrict__ px_in, const float* __restrict__ py_in,
    float* __restrict__ u_out,  float* __restrict__ ub_out,
    float* __restrict__ px_out, float* __restrict__ py_out,
    const float* __restrict__ nh_g, const float* __restrict__ sig_arr,
    int T, int mode)   // T must be even >= 4. mode 1 = init from nh; 2 = final
{
  __shared__ float sA[TY*PSTR], sB[TY*PSTR], sP[TY*PSTR];
  const int t = threadIdx.x;
  const int b = blockIdx.z;
  const int gi0 = blockIdx.y*CY - HY;
  const int gj0 = blockIdx.x*CX - HX;
  const float invs = 1.0f / sig_arr[b];
  const int pi = t >> 4, pj = t & 15;      // 64 rows x 16 col-groups
  const int c0 = 4*pj;                     // 1x4 px per thread
  const int lane = t & 63;
  const int lnL = (lane-1)&63, lnR = (lane+1)&63;
  const size_t bb = (size_t)b*S_;
  const int gi = gi0 + pi;

  #define STAGE(dst, srcP)                                         \
    _Pragma("unroll")                                              \
    for (int k = 0; k < 4; ++k){                                   \
      int p = t + k*1024; int li = p>>6, lj = p & 63;              \
      int sgi = gi0+li, sgj = gj0+lj;                              \
      int gic_ = min(max(sgi,0),H_-1), gjc_ = min(max(sgj,0),W_-1);\
      dst[li*PSTR+lj] = srcP[bb + (size_t)gic_*W_ + gjc_]; }

  if (mode == 1){ STAGE(sA, nh_g) }
  else          { STAGE(sA, ub_in) }

  const int rD = min(pi+1,TY-1);
  const int a_o  = pi*PSTR + c0;
  const int a_up = max(pi-1,0)*PSTR + c0;
  const int a_dn = rD*PSTR + c0;

  // ---- prologue: weights from nh, direct global loads ----
  int gic  = min(max(gi,0),H_-1);
  int gjc4 = min(max(gj0+c0,0), W_-4);            // aligned float4 col
  size_t go = bb + (size_t)gic*W_ + gjc4;
  float nh_r[4], ax[4], ay[4];
  {
    int giD = min(max(min(gi+1, gi0+TY-1),0),H_-1);
    int gjR = min(max(min(gj0+c0+4, gj0+TX-1),0),W_-1);
    float4 n0 = *(const float4*)&nh_g[go];
    float4 nD = *(const float4*)&nh_g[bb + (size_t)giD*W_ + gjc4];
    float nR = nh_g[bb + (size_t)gic*W_ + gjR];
    float n0a[4] = {n0.x,n0.y,n0.z,n0.w};
    float nDa[4] = {nD.x,nD.y,nD.z,nD.w};
    #pragma unroll
    for (int c = 0; c < 4; ++c){
      nh_r[c] = n0a[c];
      int gj = gj0 + c0 + c;
      float nhR = (c<3) ? n0a[c+1] : nR;
      bool jb = (gj < 0) || (gj >= W_-1);
      ax[c] = jb ? 0.f : AW_(nhR - n0a[c]);
      ay[c] = (gi < 0 || gi >= H_-1) ? 0.f : AW_(nDa[c] - n0a[c]);
    }
  }

  // ---- state ----
  float u_r[4], px_r[4], py_r[4], ub_r[4];
  if (mode == 1){
    #pragma unroll
    for (int c = 0; c < 4; ++c){
      u_r[c] = nh_r[c]; ub_r[c] = nh_r[c];
      px_r[c] = 0.f; py_r[c] = 0.f;
    }
  } else {
    float4 uv  = *(const float4*)&u_in[go];
    float4 pxv = *(const float4*)&px_in[go];
    float4 pyv = *(const float4*)&py_in[go];
    u_r[0]=uv.x;  u_r[1]=uv.y;  u_r[2]=uv.z;  u_r[3]=uv.w;
    px_r[0]=pxv.x; px_r[1]=pxv.y; px_r[2]=pxv.z; px_r[3]=pxv.w;
    py_r[0]=pyv.x; py_r[1]=pyv.y; py_r[2]=pyv.z; py_r[3]=pyv.w;
  }
  __syncthreads();           // sA staged
  if (mode != 1){
    float4 ubv = *(const float4*)&sA[a_o];
    ub_r[0]=ubv.x; ub_r[1]=ubv.y; ub_r[2]=ubv.z; ub_r[3]=ubv.w;
  }

  // one PD iteration; RBUF/WBUF compile-time; PUB=0 skips dead publish+barrier
  #define PDITER(RBUF, WBUF, PUB)                                         \
  {                                                                       \
    float4 dn = *(const float4*)&RBUF[a_dn];                              \
    float ubR = __shfl(ub_r[0], lnR);                                     \
    if (pj == 15) ubR = ub_r[3];                                          \
    float dna[4] = {dn.x,dn.y,dn.z,dn.w};                                 \
    _Pragma("unroll")                                                     \
    for (int c = 0; c < 4; ++c){                                          \
      float ubRn = (c<3) ? ub_r[c+1] : ubR;                               \
      px_r[c] = fminf(fmaxf(fmaf(SIG_, ubRn-ub_r[c], px_r[c]), -ax[c]), ax[c]); \
      py_r[c] = fminf(fmaxf(fmaf(SIG_, dna[c]-ub_r[c], py_r[c]), -ay[c]), ay[c]); \
    }                                                                     \
    *(float4*)&sP[a_o] = make_float4(py_r[0],py_r[1],py_r[2],py_r[3]);    \
    float pxl3 = __shfl(px_r[3], lnL);                                    \
    __syncthreads();                                                      \
    float4 pu = *(const float4*)&sP[a_up];                                \
    float pyu[4] = {pu.x,pu.y,pu.z,pu.w};                                 \
    _Pragma("unroll")                                                     \
    for (int c = 0; c < 4; ++c){                                          \
      float pxl = (c>0) ? px_r[c-1] : pxl3;                               \
      float div = px_r[c] + py_r[c] - pxl - pyu[c];                       \
      float un = fmaf(TAU_, div + nh_r[c], u_r[c]) * INV1PT_;             \
      ub_r[c] = 2.f*un - u_r[c];                                          \
      u_r[c] = un;                                                        \
    }                                                                     \
    if (PUB){                                                             \
      *(float4*)&WBUF[a_o] = make_float4(ub_r[0],ub_r[1],ub_r[2],ub_r[3]);\
      __syncthreads();                                                    \
    }                                                                     \
  }

  for (int s = 0; s < T-2; s += 2){
    PDITER(sA, sB, 1)
    PDITER(sB, sA, 1)
  }
  PDITER(sA, sB, 1)
  PDITER(sB, sA, 0)

  // epilogue: core rows pi in [HY, HY+CY), core col-groups pj in [3, 12]
  if (pi >= HY && pi < HY+CY && pj >= 3 && pj <= 12 && gi < H_){
    int gj = gj0 + c0;
    if (gj < W_){
      size_t g = bb + (size_t)gi*W_ + gj;
      if (mode == 2){
        *(float4*)&u_out[g] = make_float4(
          fminf(fmaxf(u_r[0],0.f),1.f), fminf(fmaxf(u_r[1],0.f),1.f),
          fminf(fmaxf(u_r[2],0.f),1.f), fminf(fmaxf(u_r[3],0.f),1.f));
      } else {
        *(float4*)&u_out[g]  = make_float4(u_r[0], u_r[1], u_r[2], u_r[3]);
        *(float4*)&ub_out[g] = make_float4(ub_r[0],ub_r[1],ub_r[2],ub_r[3]);
        *(float4*)&px_out[g] = make_float4(px_r[0],px_r[1],px_r[2],px_r[3]);
        *(float4*)&py_out[g] = make_float4(py_r[0],py_r[1],py_r[2],py_r[3]);
      }
    }
  }
}

extern "C" void kernel_launch(void* const* d_in, const int* in_sizes, int n_in,
                              void* d_out, int out_size, void* d_ws, size_t ws_size,
                              hipStream_t stream){
  const float* Iy = (const float*)d_in[0];
  float* out = (float*)d_out;
  char* ws = (char*)d_ws;
  const size_t SLOT = (size_t)B_*S_*sizeof(float);
  float* slot[8];
  for (int q = 0; q < 8; ++q) slot[q] = (float*)(ws + (size_t)q*SLOT);
  float* vx2 = (float*)(ws + (size_t)8*SLOT);  // lo,hi per batch (32 floats)
  float* sig = vx2 + 32;                       // sigma per batch (16 floats)

  // buffer plan:
  //  s0 Rh -> uB          s1 GBh -> uA         s2 xb -> ubB
  //  s3 nh (live to end)  s4 (free) -> pyB     s5 Rf -> pxA
  //  s6 Gf -> pyA         s7 hists -> pxB      out: ubA -> final u
  float* Rh  = slot[0];
  float* GBh = slot[1];
  float* Rf  = slot[5];
  float* Gf  = slot[6];
  float* xb  = slot[2];
  float* nh  = slot[3];
  unsigned int* hist_x  = (unsigned int*)(ws + (size_t)7*SLOT);              // 8.9 MiB (544 partials)
  unsigned int* hist_gm = (unsigned int*)(ws + (size_t)7*SLOT + 9437184);    // 4 MiB (256 partials)

  hmax_kernel<<<B_*H_, 256, 0, stream>>>(Iy, Rh, GBh);
  vscan_fwd_kernel<<<544, 256, 0, stream>>>(Rh, GBh, Rf, Gf);
  // bwd scan + fused x-histogram (34 partials per batch)
  vscan_bwd_kernel<<<544, 256, 0, stream>>>(Rh, GBh, Rf, Gf, Iy, xb, hist_x);
  // ranks: floor/ceil of 0.01*(N-1)=2621.43 and 0.99*(N-1)=259521.57
  pick_hist_kernel<<<B_, 256, 0, stream>>>(hist_x, 34, 2621, 2622, 259521, 259522, 4, vx2, 0);
  // fused N_hat store + grad-mag histogram (16 partials per batch)
  nhat_gmhist_kernel<<<256, 256, 0, stream>>>(xb, vx2, nh, hist_gm);
  // median ranks 131071, 131072
  pick_hist_kernel<<<B_, 256, 0, stream>>>(hist_gm, 16, 131071, 131072, 0, 0, 2, sig, 1);

  float *uA = slot[1], *ubA = out,     *pxA = slot[5], *pyA = slot[6];
  float *uB = slot[0], *ubB = slot[2], *pxB = slot[7], *pyB = slot[4];

  dim3 pdg(NBX, NBY, B_);
  pd_fused_kernel<<<pdg, 1024, 0, stream>>>(nh, nh, nh, nh,
                                            uA, ubA, pxA, pyA, nh, sig, 10, 1);
  pd_fused_kernel<<<pdg, 1024, 0, stream>>>(uA, ubA, pxA, pyA,
                                            uB, ubB, pxB, pyB, nh, sig, 10, 0);
  // last launch: clamp u straight into out (ubA=out is dead; out not read here)
  pd_fused_kernel<<<pdg, 1024, 0, stream>>>(uB, ubB, pxB, pyB,
                                            out, slot[7], slot[7], slot[7], nh, sig, 10, 2);
}

// Round 9
// 380.298 us; speedup vs baseline: 1.2190x; 1.2190x over previous
//
#include <hip/hip_runtime.h>
#include <math.h>

#define B_ 16
#define W_ 512
#define H_ 512
#define S_ (W_*H_)
#define ALPHA_ 0.15f
#define MU_ 10.0f
#define TAU_ 0.125f
#define SIG_ 0.125f
#define EPS_ 1e-6f
#define INV1PT_ (1.0f/(1.0f+TAU_))
#define NBINS 4096
#define BINSCALE 2048.0f
#define BINW (1.0f/2048.0f)

// ---- K1: horizontal 31-tap max via log-tree sliding max (float4 staging) ----
__global__ __launch_bounds__(256) void hmax_kernel(const float* __restrict__ Iy,
                                                   float* __restrict__ Rh,
                                                   float* __restrict__ GBh){
  __shared__ float bufA[2][544], bufB[2][544];
  int t = threadIdx.x;
  int b = blockIdx.x >> 9;
  int i = blockIdx.x & 511;
  const float* rowR = Iy + (size_t)b*3*S_ + (size_t)i*W_;
  const float* rowG = rowR + S_;
  const float* rowB = rowR + 2*S_;
  // interior: p4 in [4,132) -> buf[p4*4 .. +3] = row[p4*4-16 ..], 16B-aligned
  if (t < 128){
    int o4 = (t + 4)*4;
    float4 r = *(const float4*)&rowR[o4-16];
    float4 g = *(const float4*)&rowG[o4-16];
    float4 bb = *(const float4*)&rowB[o4-16];
    *(float4*)&bufA[0][o4] = r;
    *(float4*)&bufA[1][o4] = make_float4(fmaxf(g.x,bb.x), fmaxf(g.y,bb.y),
                                         fmaxf(g.z,bb.z), fmaxf(g.w,bb.w));
  } else if (t < 160){
    int e = t - 128;                       // 32 edge slots: [0,16) u [528,544)
    int p = (e < 16) ? e : (512 + e);
    bufA[0][p] = -1e30f;
    bufA[1][p] = -1e30f;
  }
  __syncthreads();
  float (*src)[544] = bufA; float (*dst)[544] = bufB;
  const int ds[5] = {1, 2, 4, 8, 15};
  #pragma unroll
  for (int sstep = 0; sstep < 5; ++sstep){
    int d = ds[sstep];
    for (int p = t; p < 544; p += 256){
      int q = min(p + d, 543);
      dst[0][p] = fmaxf(src[0][p], src[0][q]);
      dst[1][p] = fmaxf(src[1][p], src[1][q]);
    }
    __syncthreads();
    float (*tmp)[544] = src; src = dst; dst = tmp;
  }
  size_t o = (size_t)b*S_ + (size_t)i*W_;
  for (int p = t; p < 512; p += 256){
    Rh[o+p]  = src[0][p+1];
    GBh[o+p] = src[1][p+1];
  }
}

// ---- vertical van Herk forward scan (31-row aligned chunks; static trip) ----
__global__ __launch_bounds__(256) void vscan_fwd_kernel(const float* __restrict__ Rh,
                                                        const float* __restrict__ GBh,
                                                        float* __restrict__ Rf,
                                                        float* __restrict__ Gf){
  int gid = blockIdx.x*256 + threadIdx.x;     // 544 blocks = 8192 cols * 17 chunks
  int col = gid & 8191;
  int c   = gid >> 13;                        // 0..16
  int b = col >> 9, j = col & 511;
  int i0 = c*31;
  size_t base = (size_t)b*S_ + j;
  float rR = -1e30f, rG = -1e30f;
  if (c <= 15){
    for (int k = 0; k < 31; ++k){
      size_t o = base + (size_t)(i0+k)*W_;
      rR = fmaxf(rR, Rh[o]); rG = fmaxf(rG, GBh[o]);
      Rf[o] = rR; Gf[o] = rG;
    }
  } else {
    for (int k = 0; k < 16; ++k){
      size_t o = base + (size_t)(i0+k)*W_;
      rR = fmaxf(rR, Rh[o]); rG = fmaxf(rG, GBh[o]);
      Rf[o] = rR; Gf[o] = rG;
    }
  }
}

// ---- vertical bwd scan; x = |Rmax - GBmax| + R; FUSED x-histogram ----
__global__ __launch_bounds__(256) void vscan_bwd_kernel(const float* __restrict__ Rh,
                                                        const float* __restrict__ GBh,
                                                        const float* __restrict__ Rf,
                                                        const float* __restrict__ Gf,
                                                        const float* __restrict__ Iy,
                                                        float* __restrict__ xo,
                                                        unsigned int* __restrict__ hist){
  __shared__ unsigned int h[NBINS];
  int t = threadIdx.x;
  for (int p = t; p < NBINS; p += 256) h[p] = 0u;
  __syncthreads();
  int gid = blockIdx.x*256 + t;
  int col = gid & 8191;
  int c   = gid >> 13;
  int b = col >> 9, j = col & 511;
  int half = j >> 8;                           // uniform per block
  int i0 = c*31;
  size_t base = (size_t)b*S_ + j;
  const float* IyR = Iy + (size_t)b*3*S_ + j;
  float lR = -1e30f, lG = -1e30f;

  #define BWD_BODY(I, BI)                                          \
    { int i_ = (I);                                                \
      size_t o64 = base + (size_t)i_*W_;                           \
      lR = fmaxf(lR, Rh[o64]); lG = fmaxf(lG, GBh[o64]);           \
      int o_ = i_ + 15;                                            \
      size_t ob = base + (size_t)(BI)*W_;                          \
      float mR = fmaxf(lR, Rf[ob]);                                \
      float mG = fmaxf(lG, Gf[ob]);                                \
      float xv = fabsf(mR - mG) + IyR[(size_t)o_*W_];              \
      xo[base + (size_t)o_*W_] = xv;                               \
      int bin = (int)(xv*BINSCALE);                                \
      bin = min(max(bin, 0), NBINS-1);                             \
      atomicAdd(&h[bin], 1u); }

  if (c <= 14){
    for (int k = 30; k >= 0; --k) BWD_BODY(i0+k, i0+k+30)
  } else if (c == 15){
    for (int k = 30; k >= 0; --k) BWD_BODY(i0+k, min(i0+k+30, H_-1))
  } else {
    for (int i = H_-1; i >= i0; --i){
      size_t o64 = base + (size_t)i*W_;
      lR = fmaxf(lR, Rh[o64]); lG = fmaxf(lG, GBh[o64]);
      int o = i + 15;
      if (o < H_){
        size_t ob = base + (size_t)(H_-1)*W_;
        float mR = fmaxf(lR, Rf[ob]);
        float mG = fmaxf(lG, Gf[ob]);
        float xv = fabsf(mR - mG) + IyR[(size_t)o*W_];
        xo[base + (size_t)o*W_] = xv;
        int bin = (int)(xv*BINSCALE);
        bin = min(max(bin, 0), NBINS-1);
        atomicAdd(&h[bin], 1u);
      }
    }
  }
  if (c == 0){
    for (int o = 0; o < 15; ++o){
      size_t ob = base + (size_t)(o+15)*W_;
      float mR = Rf[ob], mG = Gf[ob];
      float xv = fabsf(mR - mG) + IyR[(size_t)o*W_];
      xo[base + (size_t)o*W_] = xv;
      int bin = (int)(xv*BINSCALE);
      bin = min(max(bin, 0), NBINS-1);
      atomicAdd(&h[bin], 1u);
    }
  }
  __syncthreads();
  unsigned int* hb = hist + (size_t)(b*34 + c*2 + half)*NBINS;
  for (int q = t; q < NBINS; q += 256) hb[q] = h[q];
}

// ---- FUSED: N_hat store + grad-mag histogram in one pass over xb ----
__global__ __launch_bounds__(256) void nhat_gmhist_kernel(const float* __restrict__ xb,
                                                          const float* __restrict__ vx2,
                                                          float* __restrict__ nh,
                                                          unsigned int* __restrict__ hist){
  __shared__ unsigned int h[NBINS];
  int t = threadIdx.x;
  int b = blockIdx.x >> 4, sub = blockIdx.x & 15;
  for (int p = t; p < NBINS; p += 256) h[p] = 0u;
  __syncthreads();
  float lo = vx2[2*b], hi = vx2[2*b+1];
  float inv = 1.0f/(hi - lo + EPS_);
  const float* base = xb + (size_t)b*S_;
  float* nhb = nh + (size_t)b*S_;
  int i0 = sub*16384;
  for (int k = 0; k < 64; ++k){
    int idx = i0 + k*256 + t;
    int row = idx >> 9, col = idx & 511;
    float c = fminf(fmaxf((base[idx] - lo)*inv, 0.f), 1.f);
    float dx = 0.f, dy = 0.f;
    if (col < W_-1) dx = fminf(fmaxf((base[idx+1]  - lo)*inv, 0.f), 1.f) - c;
    if (row < H_-1) dy = fminf(fmaxf((base[idx+W_] - lo)*inv, 0.f), 1.f) - c;
    nhb[idx] = c;
    float g = sqrtf(dx*dx + dy*dy + EPS_);
    int bin = (int)(g*BINSCALE);
    bin = min(max(bin, 0), NBINS-1);
    atomicAdd(&h[bin], 1u);
  }
  __syncthreads();
  unsigned int* hb = hist + (size_t)(b*16 + sub)*NBINS;
  for (int q = t; q < NBINS; q += 256) hb[q] = h[q];
}

// ---- pick order statistics (nsub partials per batch) ----
__global__ __launch_bounds__(256) void pick_hist_kernel(
    const unsigned int* __restrict__ hist, int nsub,
    int r0, int r1, int r2, int r3,
    int nranks, float* __restrict__ outv, int which){
  __shared__ unsigned int part[256];
  __shared__ int s_own[4], s_rem[4];
  __shared__ float s_val[4];
  int t = threadIdx.x, b = blockIdx.x;
  const unsigned int* hb = hist + (size_t)b*nsub*NBINS;
  unsigned int binc[16];
  #pragma unroll
  for (int k = 0; k < 16; ++k) binc[k] = 0u;
  for (int sub = 0; sub < nsub; ++sub){
    const unsigned int* hp = hb + (size_t)sub*NBINS + t*16;
    #pragma unroll
    for (int k = 0; k < 16; ++k) binc[k] += hp[k];
  }
  unsigned int sum = 0u;
  #pragma unroll
  for (int k = 0; k < 16; ++k) sum += binc[k];
  part[t] = sum;
  __syncthreads();
  if (t == 0){
    int rk[4] = {r0, r1, r2, r3};
    for (int ri = 0; ri < nranks; ++ri){
      int rem = rk[ri]; int own = 255;
      for (int q = 0; q < 256; ++q){
        if ((unsigned int)rem < part[q]){ own = q; break; }
        rem -= (int)part[q];
      }
      s_own[ri] = own; s_rem[ri] = rem;
    }
  }
  __syncthreads();
  for (int ri = 0; ri < nranks; ++ri){
    if (t == s_own[ri]){
      int rem = s_rem[ri]; int bin = t*16 + 15;
      #pragma unroll
      for (int q = 0; q < 16; ++q){
        if ((unsigned int)rem < binc[q]){ bin = t*16 + q; break; }
        rem -= (int)binc[q];
      }
      s_val[ri] = ((float)bin + 0.5f) * BINW;
    }
  }
  __syncthreads();
  if (t == 0){
    if (which == 0){
      outv[2*b+0] = s_val[0]*0.57f + s_val[1]*0.43f;   // lo (pos frac .43)
      outv[2*b+1] = s_val[2]*0.43f + s_val[3]*0.57f;   // hi (pos frac .57)
    } else {
      outv[b] = fmaxf(0.5f*(s_val[0] + s_val[1]), EPS_); // median -> sigma
    }
  }
}

// ---- fused primal-dual: round-5-verified config ----
// 4 launches T=8,8,8,6; TILE 64 / CORE 48 / HALO 8; runtime buffer select
// (28 VGPR, 66% occupancy, 52 us/dispatch measured round 5).
#define TY 64
#define TX 64
#define HY 8
#define HX 8
#define CY 48
#define CX 48
#define NBY 11   // ceil(512/48)
#define NBX 11
#define PSTR 68  // padded LDS row stride (float4-aligned)

#define AW_(d) (ALPHA_*(1.0f + MU_*__expf(-fabsf(d)*invs)))

__global__ __launch_bounds__(1024, 2) void pd_fused_kernel(
    const float* __restrict__ u_in,  const float* __restrict__ ub_in,
    const float* __restrict__ px_in, const float* __restrict__ py_in,
    float* __restrict__ u_out,  float* __restrict__ ub_out,
    float* __restrict__ px_out, float* __restrict__ py_out,
    const float* __restrict__ nh_g, const float* __restrict__ sig_arr,
    int T, int mode)   // mode 1 = init from nh; 2 = last launch (store clamped u)
{
  __shared__ float sA[TY*PSTR], sB[TY*PSTR], sP[TY*PSTR];
  const int t = threadIdx.x;
  const int b = blockIdx.z;
  const int gi0 = blockIdx.y*CY - HY;
  const int gj0 = blockIdx.x*CX - HX;
  const float invs = 1.0f / sig_arr[b];
  const int pi = t >> 4, pj = t & 15;      // 64 rows x 16 col-groups
  const int c0 = 4*pj;                     // 1x4 px per thread
  const int lane = t & 63;
  const size_t bb = (size_t)b*S_;
  const int gi = gi0 + pi;

  // stage a full 64x64 tile (clamped-replicate halo), 4 scalar loads/thread
  #define STAGE(dst, srcP)                                         \
    _Pragma("unroll")                                              \
    for (int k = 0; k < 4; ++k){                                   \
      int p = t + k*1024; int li = p>>6, lj = p & 63;              \
      int sgi = gi0+li, sgj = gj0+lj;                              \
      int gic_ = min(max(sgi,0),H_-1), gjc_ = min(max(sgj,0),W_-1);\
      dst[li*PSTR+lj] = srcP[bb + (size_t)gic_*W_ + gjc_]; }

  // ub (or nh-as-ub) tile -> sA
  if (mode == 1){ STAGE(sA, nh_g) }
  else          { STAGE(sA, ub_in) }

  // loop-invariant LDS addresses (row-aligned b128 in the hot loop)
  const int rD = min(pi+1,TY-1);
  const int a_o  = pi*PSTR + c0;
  const int a_up = max(pi-1,0)*PSTR + c0;
  const int a_dn = rD*PSTR + c0;

  // ---- prologue: weights from nh, direct global loads ----
  int gic  = min(max(gi,0),H_-1);
  int gjc4 = min(max(gj0+c0,0), W_-4);            // aligned float4 col
  size_t go = bb + (size_t)gic*W_ + gjc4;
  float nh_r[4], ax[4], ay[4];
  {
    int giD = min(max(min(gi+1, gi0+TY-1),0),H_-1);
    int gjR = min(max(min(gj0+c0+4, gj0+TX-1),0),W_-1);
    float4 n0 = *(const float4*)&nh_g[go];
    float4 nD = *(const float4*)&nh_g[bb + (size_t)giD*W_ + gjc4];
    float nR = nh_g[bb + (size_t)gic*W_ + gjR];
    float n0a[4] = {n0.x,n0.y,n0.z,n0.w};
    float nDa[4] = {nD.x,nD.y,nD.z,nD.w};
    #pragma unroll
    for (int c = 0; c < 4; ++c){
      nh_r[c] = n0a[c];
      int gj = gj0 + c0 + c;
      float nhR = (c<3) ? n0a[c+1] : nR;
      bool jb = (gj < 0) || (gj >= W_-1);
      ax[c] = jb ? 0.f : AW_(nhR - n0a[c]);
      ay[c] = (gi < 0 || gi >= H_-1) ? 0.f : AW_(nDa[c] - n0a[c]);
    }
  }

  // ---- state: u/px/py direct global float4 (masked edges never propagate) ----
  float u_r[4], px_r[4], py_r[4], ub_r[4];
  if (mode == 1){
    #pragma unroll
    for (int c = 0; c < 4; ++c){
      u_r[c] = nh_r[c]; ub_r[c] = nh_r[c];
      px_r[c] = 0.f; py_r[c] = 0.f;
    }
  } else {
    float4 uv  = *(const float4*)&u_in[go];
    float4 pxv = *(const float4*)&px_in[go];
    float4 pyv = *(const float4*)&py_in[go];
    u_r[0]=uv.x;  u_r[1]=uv.y;  u_r[2]=uv.z;  u_r[3]=uv.w;
    px_r[0]=pxv.x; px_r[1]=pxv.y; px_r[2]=pxv.z; px_r[3]=pxv.w;
    py_r[0]=pyv.x; py_r[1]=pyv.y; py_r[2]=pyv.z; py_r[3]=pyv.w;
  }
  __syncthreads();           // sA staged
  if (mode != 1){
    float4 ubv = *(const float4*)&sA[a_o];
    ub_r[0]=ubv.x; ub_r[1]=ubv.y; ub_r[2]=ubv.z; ub_r[3]=ubv.w;
  }

  for (int s = 0; s < T; ++s){
    float* RB = (s & 1) ? sB : sA;
    float* WB = (s & 1) ? sA : sB;
    float4 dn = *(const float4*)&RB[a_dn];
    float ubR = __shfl(ub_r[0], (lane+1)&63);
    if (pj == 15) ubR = ub_r[3];
    float dna[4] = {dn.x,dn.y,dn.z,dn.w};
    #pragma unroll
    for (int c = 0; c < 4; ++c){
      float ubRn = (c<3) ? ub_r[c+1] : ubR;
      px_r[c] = fminf(fmaxf(fmaf(SIG_, ubRn-ub_r[c], px_r[c]), -ax[c]), ax[c]);
      py_r[c] = fminf(fmaxf(fmaf(SIG_, dna[c]-ub_r[c], py_r[c]), -ay[c]), ay[c]);
    }
    *(float4*)&sP[a_o] = make_float4(py_r[0],py_r[1],py_r[2],py_r[3]);
    float pxl3 = __shfl(px_r[3], (lane-1)&63);
    __syncthreads();                               // publish py
    float4 pu = *(const float4*)&sP[a_up];
    float pyu[4] = {pu.x,pu.y,pu.z,pu.w};
    #pragma unroll
    for (int c = 0; c < 4; ++c){
      float pxl = (c>0) ? px_r[c-1] : pxl3;
      float div = px_r[c] + py_r[c] - pxl - pyu[c];
      float un = fmaf(TAU_, div + nh_r[c], u_r[c]) * INV1PT_;
      ub_r[c] = 2.f*un - u_r[c];
      u_r[c] = un;
    }
    if (s < T-1){
      *(float4*)&WB[a_o] = make_float4(ub_r[0],ub_r[1],ub_r[2],ub_r[3]);
      __syncthreads();                             // publish ub
    }
  }

  // epilogue: core rows pi in [HY, HY+CY), core col-groups pj in [HX/4, (HX+CX)/4)
  if (pi >= HY && pi < HY+CY && pj >= HX/4 && pj < (HX+CX)/4 && gi < H_){
    int gj = gj0 + c0;
    if (gj < W_){
      size_t g = bb + (size_t)gi*W_ + gj;
      if (mode == 2){
        *(float4*)&u_out[g] = make_float4(
          fminf(fmaxf(u_r[0],0.f),1.f), fminf(fmaxf(u_r[1],0.f),1.f),
          fminf(fmaxf(u_r[2],0.f),1.f), fminf(fmaxf(u_r[3],0.f),1.f));
      } else {
        *(float4*)&u_out[g]  = make_float4(u_r[0], u_r[1], u_r[2], u_r[3]);
        *(float4*)&ub_out[g] = make_float4(ub_r[0],ub_r[1],ub_r[2],ub_r[3]);
        *(float4*)&px_out[g] = make_float4(px_r[0],px_r[1],px_r[2],px_r[3]);
        *(float4*)&py_out[g] = make_float4(py_r[0],py_r[1],py_r[2],py_r[3]);
      }
    }
  }
}

extern "C" void kernel_launch(void* const* d_in, const int* in_sizes, int n_in,
                              void* d_out, int out_size, void* d_ws, size_t ws_size,
                              hipStream_t stream){
  const float* Iy = (const float*)d_in[0];
  float* out = (float*)d_out;
  char* ws = (char*)d_ws;
  const size_t SLOT = (size_t)B_*S_*sizeof(float);
  float* slot[8];
  for (int q = 0; q < 8; ++q) slot[q] = (float*)(ws + (size_t)q*SLOT);
  float* vx2 = (float*)(ws + (size_t)8*SLOT);  // lo,hi per batch (32 floats)
  float* sig = vx2 + 32;                       // sigma per batch (16 floats)

  // buffer plan (round-4-verified lifetimes):
  //  s0 Rh -> uB          s1 GBh -> uA         s2 xb -> ubA
  //  s3 nh (live to end)  s4 hists -> ubB      s5 Rf -> pxA
  //  s6 Gf -> pyA         s7 pxB               out: pyB -> final u
  float* Rh  = slot[0];
  float* GBh = slot[1];
  float* Rf  = slot[5];
  float* Gf  = slot[6];
  float* xb  = slot[2];
  float* nh  = slot[3];
  unsigned int* hist_x  = (unsigned int*)(ws + (size_t)4*SLOT);              // 8.9 MiB (544 partials)
  unsigned int* hist_gm = (unsigned int*)(ws + (size_t)4*SLOT + 9437184);    // 4 MiB (256 partials)

  hmax_kernel<<<B_*H_, 256, 0, stream>>>(Iy, Rh, GBh);
  vscan_fwd_kernel<<<544, 256, 0, stream>>>(Rh, GBh, Rf, Gf);
  // bwd scan + fused x-histogram (34 partials per batch)
  vscan_bwd_kernel<<<544, 256, 0, stream>>>(Rh, GBh, Rf, Gf, Iy, xb, hist_x);
  // ranks: floor/ceil of 0.01*(N-1)=2621.43 and 0.99*(N-1)=259521.57
  pick_hist_kernel<<<B_, 256, 0, stream>>>(hist_x, 34, 2621, 2622, 259521, 259522, 4, vx2, 0);
  // fused N_hat store + grad-mag histogram (16 partials per batch)
  nhat_gmhist_kernel<<<256, 256, 0, stream>>>(xb, vx2, nh, hist_gm);
  // median ranks 131071, 131072
  pick_hist_kernel<<<B_, 256, 0, stream>>>(hist_gm, 16, 131071, 131072, 0, 0, 2, sig, 1);

  float *uA = slot[1], *ubA = slot[2], *pxA = slot[5], *pyA = slot[6];
  float *uB = slot[0], *ubB = slot[4], *pxB = slot[7], *pyB = out;

  dim3 pdg(NBX, NBY, B_);
  pd_fused_kernel<<<pdg, 1024, 0, stream>>>(nh, nh, nh, nh,
                                            uA, ubA, pxA, pyA, nh, sig, 8, 1);
  pd_fused_kernel<<<pdg, 1024, 0, stream>>>(uA, ubA, pxA, pyA,
                                            uB, ubB, pxB, pyB, nh, sig, 8, 0);
  pd_fused_kernel<<<pdg, 1024, 0, stream>>>(uB, ubB, pxB, pyB,
                                            uA, ubA, pxA, pyA, nh, sig, 8, 0);
  // last launch: clamp u straight into out (pyB=out is dead; out not read here)
  pd_fused_kernel<<<pdg, 1024, 0, stream>>>(uA, ubA, pxA, pyA,
                                            out, slot[7], slot[7], slot[7], nh, sig, 6, 2);
}

// Round 10
// 345.222 us; speedup vs baseline: 1.3428x; 1.1016x over previous
//
#include <hip/hip_runtime.h>
#include <math.h>

#define B_ 16
#define W_ 512
#define H_ 512
#define S_ (W_*H_)
#define ALPHA_ 0.15f
#define MU_ 10.0f
#define TAU_ 0.125f
#define SIG_ 0.125f
#define EPS_ 1e-6f
#define INV1PT_ (1.0f/(1.0f+TAU_))
#define NBINS 4096
#define BINSCALE 2048.0f
#define BINW (1.0f/2048.0f)

// ---- K1: horizontal 31-tap max via log-tree sliding max (float4 staging) ----
__global__ __launch_bounds__(256) void hmax_kernel(const float* __restrict__ Iy,
                                                   float* __restrict__ Rh,
                                                   float* __restrict__ GBh){
  __shared__ float bufA[2][544], bufB[2][544];
  int t = threadIdx.x;
  int b = blockIdx.x >> 9;
  int i = blockIdx.x & 511;
  const float* rowR = Iy + (size_t)b*3*S_ + (size_t)i*W_;
  const float* rowG = rowR + S_;
  const float* rowB = rowR + 2*S_;
  // interior: p4 in [4,132) -> buf[p4*4 .. +3] = row[p4*4-16 ..], 16B-aligned
  if (t < 128){
    int o4 = (t + 4)*4;
    float4 r = *(const float4*)&rowR[o4-16];
    float4 g = *(const float4*)&rowG[o4-16];
    float4 bb = *(const float4*)&rowB[o4-16];
    *(float4*)&bufA[0][o4] = r;
    *(float4*)&bufA[1][o4] = make_float4(fmaxf(g.x,bb.x), fmaxf(g.y,bb.y),
                                         fmaxf(g.z,bb.z), fmaxf(g.w,bb.w));
  } else if (t < 160){
    int e = t - 128;                       // 32 edge slots: [0,16) u [528,544)
    int p = (e < 16) ? e : (512 + e);
    bufA[0][p] = -1e30f;
    bufA[1][p] = -1e30f;
  }
  __syncthreads();
  float (*src)[544] = bufA; float (*dst)[544] = bufB;
  const int ds[5] = {1, 2, 4, 8, 15};
  #pragma unroll
  for (int sstep = 0; sstep < 5; ++sstep){
    int d = ds[sstep];
    for (int p = t; p < 544; p += 256){
      int q = min(p + d, 543);
      dst[0][p] = fmaxf(src[0][p], src[0][q]);
      dst[1][p] = fmaxf(src[1][p], src[1][q]);
    }
    __syncthreads();
    float (*tmp)[544] = src; src = dst; dst = tmp;
  }
  size_t o = (size_t)b*S_ + (size_t)i*W_;
  for (int p = t; p < 512; p += 256){
    Rh[o+p]  = src[0][p+1];
    GBh[o+p] = src[1][p+1];
  }
}

// ---- FUSED vertical van Herk (fwd+bwd in one pass) + x + x-histogram ----
// Block = 256 columns of one 31-row chunk. Own chunk staged in LDS (per-thread
// private columns, no barriers needed), suffix computed in place; prefix of
// chunk c+1 streamed from global. Eliminates Rf/Gf (64 MB round-trip) and the
// second Rh/GBh read of the old bwd kernel. All ops are max/abs/add on the
// same operands in the same order as the split kernels -> bit-identical x.
__global__ __launch_bounds__(256) void vscan_fused_kernel(
    const float* __restrict__ Rh, const float* __restrict__ GBh,
    const float* __restrict__ Iy, float* __restrict__ xo,
    unsigned int* __restrict__ hist){
  __shared__ float sR[31*256], sG[31*256];
  __shared__ unsigned int h[NBINS];
  int t = threadIdx.x;
  for (int p = t; p < NBINS; p += 256) h[p] = 0u;
  __syncthreads();
  int gid = blockIdx.x*256 + t;
  int col = gid & 8191;
  int c   = gid >> 13;                 // 0..16 (uniform per block)
  int b = col >> 9, j = col & 511;
  int half = j >> 8;
  int i0 = c*31;
  size_t base = (size_t)b*S_ + j;
  const float* IyR = Iy + (size_t)b*3*S_ + j;

  #define EMIT(OROW, XV)                                   \
    { float xv_ = (XV);                                    \
      xo[base + (size_t)(OROW)*W_] = xv_;                  \
      int bin_ = (int)(xv_*BINSCALE);                      \
      bin_ = min(max(bin_, 0), NBINS-1);                   \
      atomicAdd(&h[bin_], 1u); }

  if (c < 16){
    // ---- stage raw chunk rows (fold head outputs o=0..14 for c==0) ----
    if (c == 0){
      float hR = -1e30f, hG = -1e30f;
      for (int k = 0; k < 31; ++k){
        size_t o64 = base + (size_t)k*W_;
        float vR = Rh[o64], vG = GBh[o64];
        sR[k*256+t] = vR; sG[k*256+t] = vG;
        hR = fmaxf(hR, vR); hG = fmaxf(hG, vG);
        if (k >= 15 && k <= 29){
          int o = k - 15;                       // prefix through row o+15
          EMIT(o, fabsf(hR - hG) + IyR[(size_t)o*W_])
        }
      }
    } else {
      for (int k = 0; k < 31; ++k){
        size_t o64 = base + (size_t)(i0+k)*W_;
        sR[k*256+t] = Rh[o64]; sG[k*256+t] = GBh[o64];
      }
    }
    // ---- in-place suffix: S[k] = max(raw[k..30]) (per-thread private col) ----
    {
      float runR = -1e30f, runG = -1e30f;
      for (int k = 30; k >= 0; --k){
        runR = fmaxf(runR, sR[k*256+t]);
        runG = fmaxf(runG, sG[k*256+t]);
        sR[k*256+t] = runR; sG[k*256+t] = runG;
      }
    }
    // ---- emit: k=0 needs no prefix (S[0] = full-chunk max = old max(sfx,pfx));
    // k=1..30 stream chunk c+1 row i0+30+k into running prefix ----
    {
      float mR = sR[t], mG = sG[t];
      int o0 = i0 + 15;
      EMIT(o0, fabsf(mR - mG) + IyR[(size_t)o0*W_])
      float pR = -1e30f, pG = -1e30f;
      for (int k = 1; k <= 30; ++k){
        int ri = i0 + 30 + k;
        if (ri < H_){                      // c==15: prefix freezes at row 511
          size_t o64 = base + (size_t)ri*W_;
          pR = fmaxf(pR, Rh[o64]); pG = fmaxf(pG, GBh[o64]);
        }
        float mRk = fmaxf(sR[k*256+t], pR);
        float mGk = fmaxf(sG[k*256+t], pG);
        int ok = i0 + k + 15;
        EMIT(ok, fabsf(mRk - mGk) + IyR[(size_t)ok*W_])
      }
    }
  } else {
    // c == 16: rows 496..511; only o=511 emits; value = full-chunk max
    float runR = -1e30f, runG = -1e30f;
    for (int i = H_-1; i >= 496; --i){
      size_t o64 = base + (size_t)i*W_;
      runR = fmaxf(runR, Rh[o64]); runG = fmaxf(runG, GBh[o64]);
    }
    EMIT(H_-1, fabsf(runR - runG) + IyR[(size_t)(H_-1)*W_])
  }
  __syncthreads();
  unsigned int* hb = hist + (size_t)(b*34 + c*2 + half)*NBINS;
  for (int q = t; q < NBINS; q += 256) hb[q] = h[q];
}

// ---- FUSED: N_hat store + grad-mag histogram, float4-vectorized ----
__global__ __launch_bounds__(256) void nhat_gmhist_kernel(const float* __restrict__ xb,
                                                          const float* __restrict__ vx2,
                                                          float* __restrict__ nh,
                                                          unsigned int* __restrict__ hist){
  __shared__ unsigned int h[NBINS];
  int t = threadIdx.x;
  int b = blockIdx.x >> 4, sub = blockIdx.x & 15;
  for (int p = t; p < NBINS; p += 256) h[p] = 0u;
  __syncthreads();
  float lo = vx2[2*b], hi = vx2[2*b+1];
  float inv = 1.0f/(hi - lo + EPS_);
  const float* base = xb + (size_t)b*S_;
  float* nhb = nh + (size_t)b*S_;
  int i0 = sub*16384;
  #define NCLP(V) fminf(fmaxf(((V) - lo)*inv, 0.f), 1.f)
  for (int k = 0; k < 16; ++k){
    int idx = i0 + (k*256 + t)*4;
    int row = idx >> 9, col0 = idx & 511;        // col0 in {0,4,...,508}
    float4 v = *(const float4*)&base[idx];
    float c0 = NCLP(v.x), c1 = NCLP(v.y), c2 = NCLP(v.z), c3 = NCLP(v.w);
    float cn = (col0 < 508) ? NCLP(base[idx+4]) : 0.f;
    float d0x = c1 - c0, d1x = c2 - c1, d2x = c3 - c2;
    float d3x = (col0 < 508) ? (cn - c3) : 0.f;
    float d0y = 0.f, d1y = 0.f, d2y = 0.f, d3y = 0.f;
    if (row < H_-1){
      float4 w = *(const float4*)&base[idx+W_];
      d0y = NCLP(w.x) - c0; d1y = NCLP(w.y) - c1;
      d2y = NCLP(w.z) - c2; d3y = NCLP(w.w) - c3;
    }
    *(float4*)&nhb[idx] = make_float4(c0, c1, c2, c3);
    float g0 = sqrtf(d0x*d0x + d0y*d0y + EPS_);
    float g1 = sqrtf(d1x*d1x + d1y*d1y + EPS_);
    float g2 = sqrtf(d2x*d2x + d2y*d2y + EPS_);
    float g3 = sqrtf(d3x*d3x + d3y*d3y + EPS_);
    int b0 = min(max((int)(g0*BINSCALE), 0), NBINS-1);
    int b1 = min(max((int)(g1*BINSCALE), 0), NBINS-1);
    int b2 = min(max((int)(g2*BINSCALE), 0), NBINS-1);
    int b3 = min(max((int)(g3*BINSCALE), 0), NBINS-1);
    atomicAdd(&h[b0], 1u); atomicAdd(&h[b1], 1u);
    atomicAdd(&h[b2], 1u); atomicAdd(&h[b3], 1u);
  }
  __syncthreads();
  unsigned int* hb = hist + (size_t)(b*16 + sub)*NBINS;
  for (int q = t; q < NBINS; q += 256) hb[q] = h[q];
}

// ---- pick order statistics (nsub partials per batch) ----
__global__ __launch_bounds__(256) void pick_hist_kernel(
    const unsigned int* __restrict__ hist, int nsub,
    int r0, int r1, int r2, int r3,
    int nranks, float* __restrict__ outv, int which){
  __shared__ unsigned int part[256];
  __shared__ int s_own[4], s_rem[4];
  __shared__ float s_val[4];
  int t = threadIdx.x, b = blockIdx.x;
  const unsigned int* hb = hist + (size_t)b*nsub*NBINS;
  unsigned int binc[16];
  #pragma unroll
  for (int k = 0; k < 16; ++k) binc[k] = 0u;
  for (int sub = 0; sub < nsub; ++sub){
    const unsigned int* hp = hb + (size_t)sub*NBINS + t*16;
    #pragma unroll
    for (int k = 0; k < 16; ++k) binc[k] += hp[k];
  }
  unsigned int sum = 0u;
  #pragma unroll
  for (int k = 0; k < 16; ++k) sum += binc[k];
  part[t] = sum;
  __syncthreads();
  if (t == 0){
    int rk[4] = {r0, r1, r2, r3};
    for (int ri = 0; ri < nranks; ++ri){
      int rem = rk[ri]; int own = 255;
      for (int q = 0; q < 256; ++q){
        if ((unsigned int)rem < part[q]){ own = q; break; }
        rem -= (int)part[q];
      }
      s_own[ri] = own; s_rem[ri] = rem;
    }
  }
  __syncthreads();
  for (int ri = 0; ri < nranks; ++ri){
    if (t == s_own[ri]){
      int rem = s_rem[ri]; int bin = t*16 + 15;
      #pragma unroll
      for (int q = 0; q < 16; ++q){
        if ((unsigned int)rem < binc[q]){ bin = t*16 + q; break; }
        rem -= (int)binc[q];
      }
      s_val[ri] = ((float)bin + 0.5f) * BINW;
    }
  }
  __syncthreads();
  if (t == 0){
    if (which == 0){
      outv[2*b+0] = s_val[0]*0.57f + s_val[1]*0.43f;   // lo (pos frac .43)
      outv[2*b+1] = s_val[2]*0.43f + s_val[3]*0.57f;   // hi (pos frac .57)
    } else {
      outv[b] = fmaxf(0.5f*(s_val[0] + s_val[1]), EPS_); // median -> sigma
    }
  }
}

// ---- fused primal-dual: round-5/9-verified config (unchanged) ----
// 4 launches T=8,8,8,6; TILE 64 / CORE 48 / HALO 8; runtime buffer select
// (28 VGPR, 66% occupancy, 52 us/dispatch measured rounds 5 and 9).
#define TY 64
#define TX 64
#define HY 8
#define HX 8
#define CY 48
#define CX 48
#define NBY 11   // ceil(512/48)
#define NBX 11
#define PSTR 68  // padded LDS row stride (float4-aligned)

#define AW_(d) (ALPHA_*(1.0f + MU_*__expf(-fabsf(d)*invs)))

__global__ __launch_bounds__(1024, 2) void pd_fused_kernel(
    const float* __restrict__ u_in,  const float* __restrict__ ub_in,
    const float* __restrict__ px_in, const float* __restrict__ py_in,
    float* __restrict__ u_out,  float* __restrict__ ub_out,
    float* __restrict__ px_out, float* __restrict__ py_out,
    const float* __restrict__ nh_g, const float* __restrict__ sig_arr,
    int T, int mode)   // mode 1 = init from nh; 2 = last launch (store clamped u)
{
  __shared__ float sA[TY*PSTR], sB[TY*PSTR], sP[TY*PSTR];
  const int t = threadIdx.x;
  const int b = blockIdx.z;
  const int gi0 = blockIdx.y*CY - HY;
  const int gj0 = blockIdx.x*CX - HX;
  const float invs = 1.0f / sig_arr[b];
  const int pi = t >> 4, pj = t & 15;      // 64 rows x 16 col-groups
  const int c0 = 4*pj;                     // 1x4 px per thread
  const int lane = t & 63;
  const size_t bb = (size_t)b*S_;
  const int gi = gi0 + pi;

  // stage a full 64x64 tile (clamped-replicate halo), 4 scalar loads/thread
  #define STAGE(dst, srcP)                                         \
    _Pragma("unroll")                                              \
    for (int k = 0; k < 4; ++k){                                   \
      int p = t + k*1024; int li = p>>6, lj = p & 63;              \
      int sgi = gi0+li, sgj = gj0+lj;                              \
      int gic_ = min(max(sgi,0),H_-1), gjc_ = min(max(sgj,0),W_-1);\
      dst[li*PSTR+lj] = srcP[bb + (size_t)gic_*W_ + gjc_]; }

  // ub (or nh-as-ub) tile -> sA
  if (mode == 1){ STAGE(sA, nh_g) }
  else          { STAGE(sA, ub_in) }

  // loop-invariant LDS addresses (row-aligned b128 in the hot loop)
  const int rD = min(pi+1,TY-1);
  const int a_o  = pi*PSTR + c0;
  const int a_up = max(pi-1,0)*PSTR + c0;
  const int a_dn = rD*PSTR + c0;

  // ---- prologue: weights from nh, direct global loads ----
  int gic  = min(max(gi,0),H_-1);
  int gjc4 = min(max(gj0+c0,0), W_-4);            // aligned float4 col
  size_t go = bb + (size_t)gic*W_ + gjc4;
  float nh_r[4], ax[4], ay[4];
  {
    int giD = min(max(min(gi+1, gi0+TY-1),0),H_-1);
    int gjR = min(max(min(gj0+c0+4, gj0+TX-1),0),W_-1);
    float4 n0 = *(const float4*)&nh_g[go];
    float4 nD = *(const float4*)&nh_g[bb + (size_t)giD*W_ + gjc4];
    float nR = nh_g[bb + (size_t)gic*W_ + gjR];
    float n0a[4] = {n0.x,n0.y,n0.z,n0.w};
    float nDa[4] = {nD.x,nD.y,nD.z,nD.w};
    #pragma unroll
    for (int c = 0; c < 4; ++c){
      nh_r[c] = n0a[c];
      int gj = gj0 + c0 + c;
      float nhR = (c<3) ? n0a[c+1] : nR;
      bool jb = (gj < 0) || (gj >= W_-1);
      ax[c] = jb ? 0.f : AW_(nhR - n0a[c]);
      ay[c] = (gi < 0 || gi >= H_-1) ? 0.f : AW_(nDa[c] - n0a[c]);
    }
  }

  // ---- state: u/px/py direct global float4 (masked edges never propagate) ----
  float u_r[4], px_r[4], py_r[4], ub_r[4];
  if (mode == 1){
    #pragma unroll
    for (int c = 0; c < 4; ++c){
      u_r[c] = nh_r[c]; ub_r[c] = nh_r[c];
      px_r[c] = 0.f; py_r[c] = 0.f;
    }
  } else {
    float4 uv  = *(const float4*)&u_in[go];
    float4 pxv = *(const float4*)&px_in[go];
    float4 pyv = *(const float4*)&py_in[go];
    u_r[0]=uv.x;  u_r[1]=uv.y;  u_r[2]=uv.z;  u_r[3]=uv.w;
    px_r[0]=pxv.x; px_r[1]=pxv.y; px_r[2]=pxv.z; px_r[3]=pxv.w;
    py_r[0]=pyv.x; py_r[1]=pyv.y; py_r[2]=pyv.z; py_r[3]=pyv.w;
  }
  __syncthreads();           // sA staged
  if (mode != 1){
    float4 ubv = *(const float4*)&sA[a_o];
    ub_r[0]=ubv.x; ub_r[1]=ubv.y; ub_r[2]=ubv.z; ub_r[3]=ubv.w;
  }

  for (int s = 0; s < T; ++s){
    float* RB = (s & 1) ? sB : sA;
    float* WB = (s & 1) ? sA : sB;
    float4 dn = *(const float4*)&RB[a_dn];
    float ubR = __shfl(ub_r[0], (lane+1)&63);
    if (pj == 15) ubR = ub_r[3];
    float dna[4] = {dn.x,dn.y,dn.z,dn.w};
    #pragma unroll
    for (int c = 0; c < 4; ++c){
      float ubRn = (c<3) ? ub_r[c+1] : ubR;
      px_r[c] = fminf(fmaxf(fmaf(SIG_, ubRn-ub_r[c], px_r[c]), -ax[c]), ax[c]);
      py_r[c] = fminf(fmaxf(fmaf(SIG_, dna[c]-ub_r[c], py_r[c]), -ay[c]), ay[c]);
    }
    *(float4*)&sP[a_o] = make_float4(py_r[0],py_r[1],py_r[2],py_r[3]);
    float pxl3 = __shfl(px_r[3], (lane-1)&63);
    __syncthreads();                               // publish py
    float4 pu = *(const float4*)&sP[a_up];
    float pyu[4] = {pu.x,pu.y,pu.z,pu.w};
    #pragma unroll
    for (int c = 0; c < 4; ++c){
      float pxl = (c>0) ? px_r[c-1] : pxl3;
      float div = px_r[c] + py_r[c] - pxl - pyu[c];
      float un = fmaf(TAU_, div + nh_r[c], u_r[c]) * INV1PT_;
      ub_r[c] = 2.f*un - u_r[c];
      u_r[c] = un;
    }
    if (s < T-1){
      *(float4*)&WB[a_o] = make_float4(ub_r[0],ub_r[1],ub_r[2],ub_r[3]);
      __syncthreads();                             // publish ub
    }
  }

  // epilogue: core rows pi in [HY, HY+CY), core col-groups pj in [HX/4, (HX+CX)/4)
  if (pi >= HY && pi < HY+CY && pj >= HX/4 && pj < (HX+CX)/4 && gi < H_){
    int gj = gj0 + c0;
    if (gj < W_){
      size_t g = bb + (size_t)gi*W_ + gj;
      if (mode == 2){
        *(float4*)&u_out[g] = make_float4(
          fminf(fmaxf(u_r[0],0.f),1.f), fminf(fmaxf(u_r[1],0.f),1.f),
          fminf(fmaxf(u_r[2],0.f),1.f), fminf(fmaxf(u_r[3],0.f),1.f));
      } else {
        *(float4*)&u_out[g]  = make_float4(u_r[0], u_r[1], u_r[2], u_r[3]);
        *(float4*)&ub_out[g] = make_float4(ub_r[0],ub_r[1],ub_r[2],ub_r[3]);
        *(float4*)&px_out[g] = make_float4(px_r[0],px_r[1],px_r[2],px_r[3]);
        *(float4*)&py_out[g] = make_float4(py_r[0],py_r[1],py_r[2],py_r[3]);
      }
    }
  }
}

extern "C" void kernel_launch(void* const* d_in, const int* in_sizes, int n_in,
                              void* d_out, int out_size, void* d_ws, size_t ws_size,
                              hipStream_t stream){
  const float* Iy = (const float*)d_in[0];
  float* out = (float*)d_out;
  char* ws = (char*)d_ws;
  const size_t SLOT = (size_t)B_*S_*sizeof(float);
  float* slot[8];
  for (int q = 0; q < 8; ++q) slot[q] = (float*)(ws + (size_t)q*SLOT);
  float* vx2 = (float*)(ws + (size_t)8*SLOT);  // lo,hi per batch (32 floats)
  float* sig = vx2 + 32;                       // sigma per batch (16 floats)

  // buffer plan:
  //  s0 Rh -> uB          s1 GBh -> uA         s2 xb -> ubA
  //  s3 nh (live to end)  s4 hists -> ubB      s5 pxA
  //  s6 pyA               s7 pxB               out: pyB -> final u
  float* Rh  = slot[0];
  float* GBh = slot[1];
  float* xb  = slot[2];
  float* nh  = slot[3];
  unsigned int* hist_x  = (unsigned int*)(ws + (size_t)4*SLOT);              // 8.9 MiB (544 partials)
  unsigned int* hist_gm = (unsigned int*)(ws + (size_t)4*SLOT + 9437184);    // 4 MiB (256 partials)

  hmax_kernel<<<B_*H_, 256, 0, stream>>>(Iy, Rh, GBh);
  // fused vertical scans + x + x-histogram (replaces vscan_fwd + vscan_bwd)
  vscan_fused_kernel<<<544, 256, 0, stream>>>(Rh, GBh, Iy, xb, hist_x);
  // ranks: floor/ceil of 0.01*(N-1)=2621.43 and 0.99*(N-1)=259521.57
  pick_hist_kernel<<<B_, 256, 0, stream>>>(hist_x, 34, 2621, 2622, 259521, 259522, 4, vx2, 0);
  // fused N_hat store + grad-mag histogram (16 partials per batch)
  nhat_gmhist_kernel<<<256, 256, 0, stream>>>(xb, vx2, nh, hist_gm);
  // median ranks 131071, 131072
  pick_hist_kernel<<<B_, 256, 0, stream>>>(hist_gm, 16, 131071, 131072, 0, 0, 2, sig, 1);

  float *uA = slot[1], *ubA = slot[2], *pxA = slot[5], *pyA = slot[6];
  float *uB = slot[0], *ubB = slot[4], *pxB = slot[7], *pyB = out;

  dim3 pdg(NBX, NBY, B_);
  pd_fused_kernel<<<pdg, 1024, 0, stream>>>(nh, nh, nh, nh,
                                            uA, ubA, pxA, pyA, nh, sig, 8, 1);
  pd_fused_kernel<<<pdg, 1024, 0, stream>>>(uA, ubA, pxA, pyA,
                                            uB, ubB, pxB, pyB, nh, sig, 8, 0);
  pd_fused_kernel<<<pdg, 1024, 0, stream>>>(uB, ubB, pxB, pyB,
                                            uA, ubA, pxA, pyA, nh, sig, 8, 0);
  // last launch: clamp u straight into out (pyB=out is dead; out not read here)
  pd_fused_kernel<<<pdg, 1024, 0, stream>>>(uA, ubA, pxA, pyA,
                                            out, slot[7], slot[7], slot[7], nh, sig, 6, 2);
}

// Round 11
// 332.087 us; speedup vs baseline: 1.3959x; 1.0396x over previous
//
#include <hip/hip_runtime.h>
#include <math.h>

#define B_ 16
#define W_ 512
#define H_ 512
#define S_ (W_*H_)
#define ALPHA_ 0.15f
#define MU_ 10.0f
#define TAU_ 0.125f
#define SIG_ 0.125f
#define EPS_ 1e-6f
#define INV1PT_ (1.0f/(1.0f+TAU_))
#define NBINS 4096
#define BINSCALE 2048.0f
#define BINW (1.0f/2048.0f)

// ---- K1: horizontal 31-tap max via log-tree sliding max (float4 staging) ----
// First 512 blocks also zero the 512 KB global histogram region (2 x 16 x 4096
// uints) -- completes before vscan starts (stream order), re-zeroed every call.
__global__ __launch_bounds__(256) void hmax_kernel(const float* __restrict__ Iy,
                                                   float* __restrict__ Rh,
                                                   float* __restrict__ GBh,
                                                   unsigned int* __restrict__ hz){
  __shared__ float bufA[2][544], bufB[2][544];
  int t = threadIdx.x;
  int b = blockIdx.x >> 9;
  int i = blockIdx.x & 511;
  if (blockIdx.x < 512) hz[(size_t)blockIdx.x*256 + t] = 0u;
  const float* rowR = Iy + (size_t)b*3*S_ + (size_t)i*W_;
  const float* rowG = rowR + S_;
  const float* rowB = rowR + 2*S_;
  // interior: p4 in [4,132) -> buf[p4*4 .. +3] = row[p4*4-16 ..], 16B-aligned
  if (t < 128){
    int o4 = (t + 4)*4;
    float4 r = *(const float4*)&rowR[o4-16];
    float4 g = *(const float4*)&rowG[o4-16];
    float4 bb = *(const float4*)&rowB[o4-16];
    *(float4*)&bufA[0][o4] = r;
    *(float4*)&bufA[1][o4] = make_float4(fmaxf(g.x,bb.x), fmaxf(g.y,bb.y),
                                         fmaxf(g.z,bb.z), fmaxf(g.w,bb.w));
  } else if (t < 160){
    int e = t - 128;                       // 32 edge slots: [0,16) u [528,544)
    int p = (e < 16) ? e : (512 + e);
    bufA[0][p] = -1e30f;
    bufA[1][p] = -1e30f;
  }
  __syncthreads();
  float (*src)[544] = bufA; float (*dst)[544] = bufB;
  const int ds[5] = {1, 2, 4, 8, 15};
  #pragma unroll
  for (int sstep = 0; sstep < 5; ++sstep){
    int d = ds[sstep];
    for (int p = t; p < 544; p += 256){
      int q = min(p + d, 543);
      dst[0][p] = fmaxf(src[0][p], src[0][q]);
      dst[1][p] = fmaxf(src[1][p], src[1][q]);
    }
    __syncthreads();
    float (*tmp)[544] = src; src = dst; dst = tmp;
  }
  size_t o = (size_t)b*S_ + (size_t)i*W_;
  for (int p = t; p < 512; p += 256){
    Rh[o+p]  = src[0][p+1];
    GBh[o+p] = src[1][p+1];
  }
}

// ---- FUSED vertical van Herk (fwd+bwd in one pass) + x + x-histogram ----
// LDS-private hist per block; nonzero bins flushed via device atomicAdd into
// the per-batch global histogram (integer adds commute -> bit-identical).
__global__ __launch_bounds__(256) void vscan_fused_kernel(
    const float* __restrict__ Rh, const float* __restrict__ GBh,
    const float* __restrict__ Iy, float* __restrict__ xo,
    unsigned int* __restrict__ hist){
  __shared__ float sR[31*256], sG[31*256];
  __shared__ unsigned int h[NBINS];
  int t = threadIdx.x;
  for (int p = t; p < NBINS; p += 256) h[p] = 0u;
  __syncthreads();
  int gid = blockIdx.x*256 + t;
  int col = gid & 8191;
  int c   = gid >> 13;                 // 0..16 (uniform per block)
  int b = col >> 9, j = col & 511;
  int i0 = c*31;
  size_t base = (size_t)b*S_ + j;
  const float* IyR = Iy + (size_t)b*3*S_ + j;

  #define EMIT(OROW, XV)                                   \
    { float xv_ = (XV);                                    \
      xo[base + (size_t)(OROW)*W_] = xv_;                  \
      int bin_ = (int)(xv_*BINSCALE);                      \
      bin_ = min(max(bin_, 0), NBINS-1);                   \
      atomicAdd(&h[bin_], 1u); }

  if (c < 16){
    // ---- stage raw chunk rows (fold head outputs o=0..14 for c==0) ----
    if (c == 0){
      float hR = -1e30f, hG = -1e30f;
      for (int k = 0; k < 31; ++k){
        size_t o64 = base + (size_t)k*W_;
        float vR = Rh[o64], vG = GBh[o64];
        sR[k*256+t] = vR; sG[k*256+t] = vG;
        hR = fmaxf(hR, vR); hG = fmaxf(hG, vG);
        if (k >= 15 && k <= 29){
          int o = k - 15;                       // prefix through row o+15
          EMIT(o, fabsf(hR - hG) + IyR[(size_t)o*W_])
        }
      }
    } else {
      for (int k = 0; k < 31; ++k){
        size_t o64 = base + (size_t)(i0+k)*W_;
        sR[k*256+t] = Rh[o64]; sG[k*256+t] = GBh[o64];
      }
    }
    // ---- in-place suffix: S[k] = max(raw[k..30]) (per-thread private col) ----
    {
      float runR = -1e30f, runG = -1e30f;
      for (int k = 30; k >= 0; --k){
        runR = fmaxf(runR, sR[k*256+t]);
        runG = fmaxf(runG, sG[k*256+t]);
        sR[k*256+t] = runR; sG[k*256+t] = runG;
      }
    }
    // ---- emit: k=0 needs no prefix; k>=1 stream chunk c+1 into prefix ----
    {
      float mR = sR[t], mG = sG[t];
      int o0 = i0 + 15;
      EMIT(o0, fabsf(mR - mG) + IyR[(size_t)o0*W_])
      float pR = -1e30f, pG = -1e30f;
      for (int k = 1; k <= 30; ++k){
        int ri = i0 + 30 + k;
        if (ri < H_){                      // c==15: prefix freezes at row 511
          size_t o64 = base + (size_t)ri*W_;
          pR = fmaxf(pR, Rh[o64]); pG = fmaxf(pG, GBh[o64]);
        }
        float mRk = fmaxf(sR[k*256+t], pR);
        float mGk = fmaxf(sG[k*256+t], pG);
        int ok = i0 + k + 15;
        EMIT(ok, fabsf(mRk - mGk) + IyR[(size_t)ok*W_])
      }
    }
  } else {
    // c == 16: rows 496..511; only o=511 emits; value = full-chunk max
    float runR = -1e30f, runG = -1e30f;
    for (int i = H_-1; i >= 496; --i){
      size_t o64 = base + (size_t)i*W_;
      runR = fmaxf(runR, Rh[o64]); runG = fmaxf(runG, GBh[o64]);
    }
    EMIT(H_-1, fabsf(runR - runG) + IyR[(size_t)(H_-1)*W_])
  }
  __syncthreads();
  unsigned int* hb = hist + (size_t)b*NBINS;
  for (int q = t; q < NBINS; q += 256){
    unsigned int v = h[q];
    if (v) atomicAdd(&hb[q], v);
  }
}

// ---- FUSED: N_hat store + grad-mag histogram, float4-vectorized ----
__global__ __launch_bounds__(256) void nhat_gmhist_kernel(const float* __restrict__ xb,
                                                          const float* __restrict__ vx2,
                                                          float* __restrict__ nh,
                                                          unsigned int* __restrict__ hist){
  __shared__ unsigned int h[NBINS];
  int t = threadIdx.x;
  int b = blockIdx.x >> 4, sub = blockIdx.x & 15;
  for (int p = t; p < NBINS; p += 256) h[p] = 0u;
  __syncthreads();
  float lo = vx2[2*b], hi = vx2[2*b+1];
  float inv = 1.0f/(hi - lo + EPS_);
  const float* base = xb + (size_t)b*S_;
  float* nhb = nh + (size_t)b*S_;
  int i0 = sub*16384;
  #define NCLP(V) fminf(fmaxf(((V) - lo)*inv, 0.f), 1.f)
  for (int k = 0; k < 16; ++k){
    int idx = i0 + (k*256 + t)*4;
    int row = idx >> 9, col0 = idx & 511;        // col0 in {0,4,...,508}
    float4 v = *(const float4*)&base[idx];
    float c0 = NCLP(v.x), c1 = NCLP(v.y), c2 = NCLP(v.z), c3 = NCLP(v.w);
    float cn = (col0 < 508) ? NCLP(base[idx+4]) : 0.f;
    float d0x = c1 - c0, d1x = c2 - c1, d2x = c3 - c2;
    float d3x = (col0 < 508) ? (cn - c3) : 0.f;
    float d0y = 0.f, d1y = 0.f, d2y = 0.f, d3y = 0.f;
    if (row < H_-1){
      float4 w = *(const float4*)&base[idx+W_];
      d0y = NCLP(w.x) - c0; d1y = NCLP(w.y) - c1;
      d2y = NCLP(w.z) - c2; d3y = NCLP(w.w) - c3;
    }
    *(float4*)&nhb[idx] = make_float4(c0, c1, c2, c3);
    float g0 = sqrtf(d0x*d0x + d0y*d0y + EPS_);
    float g1 = sqrtf(d1x*d1x + d1y*d1y + EPS_);
    float g2 = sqrtf(d2x*d2x + d2y*d2y + EPS_);
    float g3 = sqrtf(d3x*d3x + d3y*d3y + EPS_);
    int b0 = min(max((int)(g0*BINSCALE), 0), NBINS-1);
    int b1 = min(max((int)(g1*BINSCALE), 0), NBINS-1);
    int b2 = min(max((int)(g2*BINSCALE), 0), NBINS-1);
    int b3 = min(max((int)(g3*BINSCALE), 0), NBINS-1);
    atomicAdd(&h[b0], 1u); atomicAdd(&h[b1], 1u);
    atomicAdd(&h[b2], 1u); atomicAdd(&h[b3], 1u);
  }
  __syncthreads();
  unsigned int* hb = hist + (size_t)b*NBINS;
  for (int q = t; q < NBINS; q += 256){
    unsigned int v = h[q];
    if (v) atomicAdd(&hb[q], v);
  }
}

// ---- pick order statistics from a single per-batch histogram ----
__global__ __launch_bounds__(256) void pick_hist_kernel(
    const unsigned int* __restrict__ hist,
    int r0, int r1, int r2, int r3,
    int nranks, float* __restrict__ outv, int which){
  __shared__ unsigned int part[256];
  __shared__ int s_own[4], s_rem[4];
  __shared__ float s_val[4];
  int t = threadIdx.x, b = blockIdx.x;
  const unsigned int* hb = hist + (size_t)b*NBINS;
  unsigned int binc[16];
  #pragma unroll
  for (int k = 0; k < 16; ++k) binc[k] = hb[t*16 + k];
  unsigned int sum = 0u;
  #pragma unroll
  for (int k = 0; k < 16; ++k) sum += binc[k];
  part[t] = sum;
  __syncthreads();
  if (t == 0){
    int rk[4] = {r0, r1, r2, r3};
    for (int ri = 0; ri < nranks; ++ri){
      int rem = rk[ri]; int own = 255;
      for (int q = 0; q < 256; ++q){
        if ((unsigned int)rem < part[q]){ own = q; break; }
        rem -= (int)part[q];
      }
      s_own[ri] = own; s_rem[ri] = rem;
    }
  }
  __syncthreads();
  for (int ri = 0; ri < nranks; ++ri){
    if (t == s_own[ri]){
      int rem = s_rem[ri]; int bin = t*16 + 15;
      #pragma unroll
      for (int q = 0; q < 16; ++q){
        if ((unsigned int)rem < binc[q]){ bin = t*16 + q; break; }
        rem -= (int)binc[q];
      }
      s_val[ri] = ((float)bin + 0.5f) * BINW;
    }
  }
  __syncthreads();
  if (t == 0){
    if (which == 0){
      outv[2*b+0] = s_val[0]*0.57f + s_val[1]*0.43f;   // lo (pos frac .43)
      outv[2*b+1] = s_val[2]*0.43f + s_val[3]*0.57f;   // hi (pos frac .57)
    } else {
      outv[b] = fmaxf(0.5f*(s_val[0] + s_val[1]), EPS_); // median -> sigma
    }
  }
}

// ---- fused primal-dual: round-5/9-verified config (unchanged, byte-for-byte) ----
// 4 launches T=8,8,8,6; TILE 64 / CORE 48 / HALO 8; runtime buffer select
// (28 VGPR, 66% occupancy, 52 us/dispatch measured rounds 5, 9, 10).
#define TY 64
#define TX 64
#define HY 8
#define HX 8
#define CY 48
#define CX 48
#define NBY 11   // ceil(512/48)
#define NBX 11
#define PSTR 68  // padded LDS row stride (float4-aligned)

#define AW_(d) (ALPHA_*(1.0f + MU_*__expf(-fabsf(d)*invs)))

__global__ __launch_bounds__(1024, 2) void pd_fused_kernel(
    const float* __restrict__ u_in,  const float* __restrict__ ub_in,
    const float* __restrict__ px_in, const float* __restrict__ py_in,
    float* __restrict__ u_out,  float* __restrict__ ub_out,
    float* __restrict__ px_out, float* __restrict__ py_out,
    const float* __restrict__ nh_g, const float* __restrict__ sig_arr,
    int T, int mode)   // mode 1 = init from nh; 2 = last launch (store clamped u)
{
  __shared__ float sA[TY*PSTR], sB[TY*PSTR], sP[TY*PSTR];
  const int t = threadIdx.x;
  const int b = blockIdx.z;
  const int gi0 = blockIdx.y*CY - HY;
  const int gj0 = blockIdx.x*CX - HX;
  const float invs = 1.0f / sig_arr[b];
  const int pi = t >> 4, pj = t & 15;      // 64 rows x 16 col-groups
  const int c0 = 4*pj;                     // 1x4 px per thread
  const int lane = t & 63;
  const size_t bb = (size_t)b*S_;
  const int gi = gi0 + pi;

  // stage a full 64x64 tile (clamped-replicate halo), 4 scalar loads/thread
  #define STAGE(dst, srcP)                                         \
    _Pragma("unroll")                                              \
    for (int k = 0; k < 4; ++k){                                   \
      int p = t + k*1024; int li = p>>6, lj = p & 63;              \
      int sgi = gi0+li, sgj = gj0+lj;                              \
      int gic_ = min(max(sgi,0),H_-1), gjc_ = min(max(sgj,0),W_-1);\
      dst[li*PSTR+lj] = srcP[bb + (size_t)gic_*W_ + gjc_]; }

  // ub (or nh-as-ub) tile -> sA
  if (mode == 1){ STAGE(sA, nh_g) }
  else          { STAGE(sA, ub_in) }

  // loop-invariant LDS addresses (row-aligned b128 in the hot loop)
  const int rD = min(pi+1,TY-1);
  const int a_o  = pi*PSTR + c0;
  const int a_up = max(pi-1,0)*PSTR + c0;
  const int a_dn = rD*PSTR + c0;

  // ---- prologue: weights from nh, direct global loads ----
  int gic  = min(max(gi,0),H_-1);
  int gjc4 = min(max(gj0+c0,0), W_-4);            // aligned float4 col
  size_t go = bb + (size_t)gic*W_ + gjc4;
  float nh_r[4], ax[4], ay[4];
  {
    int giD = min(max(min(gi+1, gi0+TY-1),0),H_-1);
    int gjR = min(max(min(gj0+c0+4, gj0+TX-1),0),W_-1);
    float4 n0 = *(const float4*)&nh_g[go];
    float4 nD = *(const float4*)&nh_g[bb + (size_t)giD*W_ + gjc4];
    float nR = nh_g[bb + (size_t)gic*W_ + gjR];
    float n0a[4] = {n0.x,n0.y,n0.z,n0.w};
    float nDa[4] = {nD.x,nD.y,nD.z,nD.w};
    #pragma unroll
    for (int c = 0; c < 4; ++c){
      nh_r[c] = n0a[c];
      int gj = gj0 + c0 + c;
      float nhR = (c<3) ? n0a[c+1] : nR;
      bool jb = (gj < 0) || (gj >= W_-1);
      ax[c] = jb ? 0.f : AW_(nhR - n0a[c]);
      ay[c] = (gi < 0 || gi >= H_-1) ? 0.f : AW_(nDa[c] - n0a[c]);
    }
  }

  // ---- state: u/px/py direct global float4 (masked edges never propagate) ----
  float u_r[4], px_r[4], py_r[4], ub_r[4];
  if (mode == 1){
    #pragma unroll
    for (int c = 0; c < 4; ++c){
      u_r[c] = nh_r[c]; ub_r[c] = nh_r[c];
      px_r[c] = 0.f; py_r[c] = 0.f;
    }
  } else {
    float4 uv  = *(const float4*)&u_in[go];
    float4 pxv = *(const float4*)&px_in[go];
    float4 pyv = *(const float4*)&py_in[go];
    u_r[0]=uv.x;  u_r[1]=uv.y;  u_r[2]=uv.z;  u_r[3]=uv.w;
    px_r[0]=pxv.x; px_r[1]=pxv.y; px_r[2]=pxv.z; px_r[3]=pxv.w;
    py_r[0]=pyv.x; py_r[1]=pyv.y; py_r[2]=pyv.z; py_r[3]=pyv.w;
  }
  __syncthreads();           // sA staged
  if (mode != 1){
    float4 ubv = *(const float4*)&sA[a_o];
    ub_r[0]=ubv.x; ub_r[1]=ubv.y; ub_r[2]=ubv.z; ub_r[3]=ubv.w;
  }

  for (int s = 0; s < T; ++s){
    float* RB = (s & 1) ? sB : sA;
    float* WB = (s & 1) ? sA : sB;
    float4 dn = *(const float4*)&RB[a_dn];
    float ubR = __shfl(ub_r[0], (lane+1)&63);
    if (pj == 15) ubR = ub_r[3];
    float dna[4] = {dn.x,dn.y,dn.z,dn.w};
    #pragma unroll
    for (int c = 0; c < 4; ++c){
      float ubRn = (c<3) ? ub_r[c+1] : ubR;
      px_r[c] = fminf(fmaxf(fmaf(SIG_, ubRn-ub_r[c], px_r[c]), -ax[c]), ax[c]);
      py_r[c] = fminf(fmaxf(fmaf(SIG_, dna[c]-ub_r[c], py_r[c]), -ay[c]), ay[c]);
    }
    *(float4*)&sP[a_o] = make_float4(py_r[0],py_r[1],py_r[2],py_r[3]);
    float pxl3 = __shfl(px_r[3], (lane-1)&63);
    __syncthreads();                               // publish py
    float4 pu = *(const float4*)&sP[a_up];
    float pyu[4] = {pu.x,pu.y,pu.z,pu.w};
    #pragma unroll
    for (int c = 0; c < 4; ++c){
      float pxl = (c>0) ? px_r[c-1] : pxl3;
      float div = px_r[c] + py_r[c] - pxl - pyu[c];
      float un = fmaf(TAU_, div + nh_r[c], u_r[c]) * INV1PT_;
      ub_r[c] = 2.f*un - u_r[c];
      u_r[c] = un;
    }
    if (s < T-1){
      *(float4*)&WB[a_o] = make_float4(ub_r[0],ub_r[1],ub_r[2],ub_r[3]);
      __syncthreads();                             // publish ub
    }
  }

  // epilogue: core rows pi in [HY, HY+CY), core col-groups pj in [HX/4, (HX+CX)/4)
  if (pi >= HY && pi < HY+CY && pj >= HX/4 && pj < (HX+CX)/4 && gi < H_){
    int gj = gj0 + c0;
    if (gj < W_){
      size_t g = bb + (size_t)gi*W_ + gj;
      if (mode == 2){
        *(float4*)&u_out[g] = make_float4(
          fminf(fmaxf(u_r[0],0.f),1.f), fminf(fmaxf(u_r[1],0.f),1.f),
          fminf(fmaxf(u_r[2],0.f),1.f), fminf(fmaxf(u_r[3],0.f),1.f));
      } else {
        *(float4*)&u_out[g]  = make_float4(u_r[0], u_r[1], u_r[2], u_r[3]);
        *(float4*)&ub_out[g] = make_float4(ub_r[0],ub_r[1],ub_r[2],ub_r[3]);
        *(float4*)&px_out[g] = make_float4(px_r[0],px_r[1],px_r[2],px_r[3]);
        *(float4*)&py_out[g] = make_float4(py_r[0],py_r[1],py_r[2],py_r[3]);
      }
    }
  }
}

extern "C" void kernel_launch(void* const* d_in, const int* in_sizes, int n_in,
                              void* d_out, int out_size, void* d_ws, size_t ws_size,
                              hipStream_t stream){
  const float* Iy = (const float*)d_in[0];
  float* out = (float*)d_out;
  char* ws = (char*)d_ws;
  const size_t SLOT = (size_t)B_*S_*sizeof(float);
  float* slot[8];
  for (int q = 0; q < 8; ++q) slot[q] = (float*)(ws + (size_t)q*SLOT);
  float* vx2 = (float*)(ws + (size_t)8*SLOT);  // lo,hi per batch (32 floats)
  float* sig = vx2 + 32;                       // sigma per batch (16 floats)

  // buffer plan:
  //  s0 Rh -> uB          s1 GBh -> uA         s2 xb -> ubA
  //  s3 nh (live to end)  s4 hists (512 KB) -> ubB
  //  s5 pxA               s6 pyA               s7 pxB    out: pyB -> final u
  float* Rh  = slot[0];
  float* GBh = slot[1];
  float* xb  = slot[2];
  float* nh  = slot[3];
  unsigned int* hist_x  = (unsigned int*)(ws + (size_t)4*SLOT);              // 16 x 4096 uints
  unsigned int* hist_gm = hist_x + (size_t)B_*NBINS;                         // 16 x 4096 uints

  // hmax also zeroes both histograms (512 KB) via its first 512 blocks
  hmax_kernel<<<B_*H_, 256, 0, stream>>>(Iy, Rh, GBh, hist_x);
  // fused vertical scans + x + x-histogram (atomic flush into per-batch hist)
  vscan_fused_kernel<<<544, 256, 0, stream>>>(Rh, GBh, Iy, xb, hist_x);
  // ranks: floor/ceil of 0.01*(N-1)=2621.43 and 0.99*(N-1)=259521.57
  pick_hist_kernel<<<B_, 256, 0, stream>>>(hist_x, 2621, 2622, 259521, 259522, 4, vx2, 0);
  // fused N_hat store + grad-mag histogram (atomic flush)
  nhat_gmhist_kernel<<<256, 256, 0, stream>>>(xb, vx2, nh, hist_gm);
  // median ranks 131071, 131072
  pick_hist_kernel<<<B_, 256, 0, stream>>>(hist_gm, 131071, 131072, 0, 0, 2, sig, 1);

  float *uA = slot[1], *ubA = slot[2], *pxA = slot[5], *pyA = slot[6];
  float *uB = slot[0], *ubB = slot[4], *pxB = slot[7], *pyB = out;

  dim3 pdg(NBX, NBY, B_);
  pd_fused_kernel<<<pdg, 1024, 0, stream>>>(nh, nh, nh, nh,
                                            uA, ubA, pxA, pyA, nh, sig, 8, 1);
  pd_fused_kernel<<<pdg, 1024, 0, stream>>>(uA, ubA, pxA, pyA,
                                            uB, ubB, pxB, pyB, nh, sig, 8, 0);
  pd_fused_kernel<<<pdg, 1024, 0, stream>>>(uB, ubB, pxB, pyB,
                                            uA, ubA, pxA, pyA, nh, sig, 8, 0);
  // last launch: clamp u straight into out (pyB=out is dead; out not read here)
  pd_fused_kernel<<<pdg, 1024, 0, stream>>>(uA, ubA, pxA, pyA,
                                            out, slot[7], slot[7], slot[7], nh, sig, 6, 2);
}